// Round 21
// baseline (156.943 us; speedup 1.0000x reference)
//
#include <hip/hip_runtime.h>
#include <math.h>

#define B_ 256
#define S_ 50
#define K_ 20
#define D_ 128
#define G3 384          // 3*D
#define M_  (B_ * S_)   // 12800 (b,s) rows
#define GROWS 16        // batch rows per GRU block
#define KT 4            // k-tiles (32 wide): 128

typedef __attribute__((ext_vector_type(8))) short bf16x8;
typedef __attribute__((ext_vector_type(4))) float f32x4;

__device__ inline unsigned short bf16_rne(float f) {
    unsigned u = __float_as_uint(f);
    return (unsigned short)((u + 0x7fffu + ((u >> 16) & 1u)) >> 16);
}
__device__ inline float fsig(float x) {
    return __builtin_amdgcn_rcpf(1.f + __expf(-x));
}
__device__ inline float ftanh(float x) {
    float t = __expf(-2.f * fabsf(x));
    float r = (1.f - t) * __builtin_amdgcn_rcpf(1.f + t);
    return x >= 0.f ? r : -r;
}

#define WG_SYNC_LDS() do { \
    __builtin_amdgcn_sched_barrier(0); \
    asm volatile("s_waitcnt lgkmcnt(0)" ::: "memory"); \
    __builtin_amdgcn_s_barrier(); \
    __builtin_amdgcn_sched_barrier(0); \
} while (0)

// ---------------------------------------------------------------------------
// Kernel P: basket pooling -> bf16. unroll-4 pipelines the dependent gathers.
// ---------------------------------------------------------------------------
__global__ __launch_bounds__(256) void pool_kernel(
    const int* __restrict__ items, const int* __restrict__ basket_len,
    const int* __restrict__ lengths, const float* __restrict__ encode,
    unsigned short* __restrict__ pooled_bf)
{
    const int tid  = threadIdx.x;
    const int pair = tid >> 7;
    const int d    = tid & 127;
    const int m    = blockIdx.x * 2 + pair;
    const int b    = m / S_;
    const int s    = m % S_;
    const int len  = lengths[b];

    float p = 0.f;
    if (s < len) {
        const int  blen = basket_len[m];
        const int* it   = items + m * K_;
        #pragma unroll 4
        for (int k = 0; k < blen; ++k)
            p += encode[(long)it[k] * D_ + d];
        p /= (float)blen;
    }
    pooled_bf[m * D_ + d] = bf16_rne(p);
}

// ---------------------------------------------------------------------------
// Kernel W: w_ih f32 -> bf16 (one-time, 49152 elems).
// ---------------------------------------------------------------------------
__global__ __launch_bounds__(256) void wih_cvt_kernel(
    const float* __restrict__ w_ih, unsigned short* __restrict__ wih_bf)
{
    int i = blockIdx.x * 256 + threadIdx.x;
    if (i < G3 * D_) wih_bf[i] = bf16_rne(w_ih[i]);
}

// ---------------------------------------------------------------------------
// Kernel G v3: MFMA GEMM, output re-laid as gx2[gate][dim][s][batch] so the
// GRU reads its 4 batch rows as ONE float4 (R20: gru is issue-bound; the 12
// scattered gx loads + addressing were the biggest removable chunk).
// Epilogue stores scatter (4B) — off the critical path, gemm has slack.
// ---------------------------------------------------------------------------
__global__ __launch_bounds__(256) void gx_gemm_mfma(
    const unsigned short* __restrict__ pooled_bf,
    const unsigned short* __restrict__ wih_bf,
    const float* __restrict__ b_ih, const float* __restrict__ b_hh,
    float* __restrict__ gx2)
{
    __shared__ unsigned short Al[128 * 128];   // [m][k] swizzled, 32KB
    __shared__ unsigned short Bl[128 * 128];   // [n][k] swizzled, 32KB

    const int tid  = threadIdx.x;
    const int bm   = blockIdx.x % 100;
    const int bn   = blockIdx.x / 100;         // 0..2 == gate g
    const int m0   = bm * 128;
    const int lane = tid & 63;
    const int wv   = tid >> 6;                 // 0..3
    const int frow = lane & 15;
    const int fhi  = lane >> 4;
    const int mh   = (wv & 1) * 64;
    const int nh   = (wv >> 1) * 64;

    #pragma unroll
    for (int i = 0; i < 8; ++i) {
        int idx = tid + i * 256;               // 0..2047
        int row = idx >> 4, c16 = idx & 15;
        int dst = (row * 256 + c16 * 16) ^ ((row & 7) << 4);
        *(bf16x8*)((char*)Al + dst) =
            *(const bf16x8*)(pooled_bf + (long)(m0 + row) * D_ + c16 * 8);
        *(bf16x8*)((char*)Bl + dst) =
            *(const bf16x8*)(wih_bf + (long)(bn * 128 + row) * D_ + c16 * 8);
    }
    __syncthreads();

    bf16x8 af[4][KT], bfr[4][KT];
    #pragma unroll
    for (int t = 0; t < 4; ++t) {
        #pragma unroll
        for (int kt = 0; kt < KT; ++kt) {
            int ra = mh + t * 16 + frow;
            int oa = (ra * 256 + kt * 64 + fhi * 16) ^ ((ra & 7) << 4);
            af[t][kt] = *(const bf16x8*)((const char*)Al + oa);
            int rb = nh + t * 16 + frow;
            int ob = (rb * 256 + kt * 64 + fhi * 16) ^ ((rb & 7) << 4);
            bfr[t][kt] = *(const bf16x8*)((const char*)Bl + ob);
        }
    }

    f32x4 acc[4][4];
    #pragma unroll
    for (int mt = 0; mt < 4; ++mt)
        #pragma unroll
        for (int nt = 0; nt < 4; ++nt) {
            f32x4 c = {0.f, 0.f, 0.f, 0.f};
            #pragma unroll
            for (int kt = 0; kt < KT; ++kt)
                c = __builtin_amdgcn_mfma_f32_16x16x32_bf16(af[mt][kt], bfr[nt][kt], c, 0, 0, 0);
            acc[mt][nt] = c;
        }

    float bias[4];
    #pragma unroll
    for (int nt = 0; nt < 4; ++nt) {
        int n = bn * 128 + nh + nt * 16 + frow;
        bias[nt] = b_ih[n] + (n < 2 * D_ ? b_hh[n] : 0.f);
    }

    // epilogue: scatter to gx2[((g*128+dim)*S + s)*B + b]
    #pragma unroll
    for (int mt = 0; mt < 4; ++mt) {
        #pragma unroll
        for (int nt = 0; nt < 4; ++nt) {
            int dim = nh + nt * 16 + frow;
            long base = ((long)bn * 128 + dim) * S_;
            #pragma unroll
            for (int r = 0; r < 4; ++r) {
                int m = m0 + mh + mt * 16 + fhi * 4 + r;
                int b = m / S_, s = m - b * S_;
                gx2[(base + s) * B_ + b] = acc[mt][nt][r] + bias[nt];
            }
        }
    }
}

// ---------------------------------------------------------------------------
// Kernel B v12: gx2[g][dim][s][b] layout -> 3 float4 loads/step (was 12
// scalar + ~40 addressing VALU). Distance-1 named double buffer (R20:
// distance-2 regressed). Everything else as v10.
// ---------------------------------------------------------------------------
__global__ __launch_bounds__(512, 1) void gru_mfma_kernel(
    const int* __restrict__ lengths, const float* __restrict__ w_hh,
    const float* __restrict__ b_hh, const float* __restrict__ h0,
    const float* __restrict__ gx2, float* __restrict__ out)
{
    const int b0   = blockIdx.x * GROWS;
    const int tid  = threadIdx.x;
    const int lane = tid & 63;
    const int wv   = tid >> 6;
    const int frow = lane & 15;
    const int fhi  = lane >> 4;
    const int dim  = wv * 16 + frow;

    __shared__ unsigned short hb[2][GROWS * D_];

    bf16x8 wf[3][KT];
    #pragma unroll
    for (int g = 0; g < 3; ++g) {
        #pragma unroll
        for (int kt = 0; kt < KT; ++kt) {
            const float* wp = w_hh + (g * D_ + dim) * D_ + kt * 32 + fhi * 8;
            bf16x8 v;
            #pragma unroll
            for (int j = 0; j < 8; ++j) v[j] = (short)bf16_rne(wp[j]);
            wf[g][kt] = v;
        }
    }

    const float bhn_s = b_hh[2 * D_ + dim];

    int   mylen[4];
    float hp[4];
    #pragma unroll
    for (int r = 0; r < 4; ++r) {
        int row = fhi * 4 + r;
        mylen[r] = lengths[b0 + row];
        hp[r]    = h0[(long)(b0 + row) * D_ + dim];
        int wb = (row * 256 + dim * 2) ^ ((row & 7) << 4);
        *(unsigned short*)((char*)hb[0] + wb) = bf16_rne(hp[r]);
    }
    const int lenmax = lengths[b0];
    __syncthreads();

    float* ys = out;
    float* hu = out + (long)B_ * S_ * D_;

    const long yrow[4] = {
        (long)(b0 + fhi * 4 + 0) * S_, (long)(b0 + fhi * 4 + 1) * S_,
        (long)(b0 + fhi * 4 + 2) * S_, (long)(b0 + fhi * 4 + 3) * S_ };

    // per-gate base pointers into gx2; step s adds s*B_ floats
    const float* gp0 = gx2 + ((long)0 * 128 + dim) * S_ * B_ + b0 + fhi * 4;
    const float* gp1 = gx2 + ((long)1 * 128 + dim) * S_ * B_ + b0 + fhi * 4;
    const float* gp2 = gx2 + ((long)2 * 128 + dim) * S_ * B_ + b0 + fhi * 4;

    #define GSTEP(s, CUR, NXT, PP) { \
        const int sn = ((s) + 1 < lenmax) ? (s) + 1 : lenmax - 1; \
        NXT[0] = *(const float4*)(gp0 + (long)sn * B_); \
        NXT[1] = *(const float4*)(gp1 + (long)sn * B_); \
        NXT[2] = *(const float4*)(gp2 + (long)sn * B_); \
        bf16x8 ah[KT]; \
        _Pragma("unroll") \
        for (int kt = 0; kt < KT; ++kt) { \
            int ab = (frow * 256 + kt * 64 + fhi * 16) ^ ((frow & 7) << 4); \
            ah[kt] = *(const bf16x8*)((const char*)hb[PP] + ab); \
        } \
        f32x4 cr = {0.f,0.f,0.f,0.f}, cz = {0.f,0.f,0.f,0.f}, cn = {0.f,0.f,0.f,0.f}; \
        _Pragma("unroll") \
        for (int kt = 0; kt < KT; ++kt) { \
            cr = __builtin_amdgcn_mfma_f32_16x16x32_bf16(ah[kt], wf[0][kt], cr, 0, 0, 0); \
            cz = __builtin_amdgcn_mfma_f32_16x16x32_bf16(ah[kt], wf[1][kt], cz, 0, 0, 0); \
            cn = __builtin_amdgcn_mfma_f32_16x16x32_bf16(ah[kt], wf[2][kt], cn, 0, 0, 0); \
        } \
        _Pragma("unroll") \
        for (int r = 0; r < 4; ++r) { \
            const int row = fhi * 4 + r; \
            const bool act = (s) < mylen[r]; \
            float rg = fsig(CUR[0][r] + cr[r]); \
            float zg = fsig(CUR[1][r] + cz[r]); \
            float ng = ftanh(CUR[2][r] + rg * (cn[r] + bhn_s)); \
            float hn = (1.f - zg) * ng + zg * hp[r]; \
            if (act) { \
                ys[(yrow[r] + (s)) * D_ + dim] = hn; \
                hp[r] = hn; \
            } \
            int wb = (row * 256 + dim * 2) ^ ((row & 7) << 4); \
            *(unsigned short*)((char*)hb[(PP) ^ 1] + wb) = bf16_rne(hp[r]); \
        } \
        WG_SYNC_LDS(); \
    }

    float4 curA[3], curB[3];
    curA[0] = *(const float4*)(gp0);
    curA[1] = *(const float4*)(gp1);
    curA[2] = *(const float4*)(gp2);

    int s = 0, pp = 0;
    while (s < lenmax) {
        GSTEP(s, curA, curB, pp);
        ++s; pp ^= 1;
        if (s >= lenmax) break;
        GSTEP(s, curB, curA, pp);
        ++s; pp ^= 1;
    }
    #undef GSTEP

    #pragma unroll
    for (int r = 0; r < 4; ++r) {
        const int row = fhi * 4 + r;
        hu[(long)(b0 + row) * D_ + dim] = hp[r];
        for (int t = mylen[r]; t < S_; ++t)
            ys[((long)(b0 + row) * S_ + t) * D_ + dim] = 0.f;
    }
}

extern "C" void kernel_launch(void* const* d_in, const int* in_sizes, int n_in,
                              void* d_out, int out_size, void* d_ws, size_t ws_size,
                              hipStream_t stream) {
    const int*   items      = (const int*)d_in[0];
    const int*   basket_len = (const int*)d_in[1];
    const int*   lengths    = (const int*)d_in[2];
    const float* encode     = (const float*)d_in[3];
    const float* w_ih       = (const float*)d_in[4];
    const float* w_hh       = (const float*)d_in[5];
    const float* b_ih       = (const float*)d_in[6];
    const float* b_hh       = (const float*)d_in[7];
    const float* h0         = (const float*)d_in[8];
    float* out = (float*)d_out;

    float*          gx2       = (float*)d_ws;                    // 19.66 MB
    unsigned short* pooled_bf = (unsigned short*)(gx2 + (long)G3 * D_ / 128 * 0 + (long)3 * 128 * S_ * B_);  // after gx2
    unsigned short* wih_bf    = pooled_bf + (long)M_ * D_;       // 96 KB

    pool_kernel<<<M_ / 2, 256, 0, stream>>>(
        items, basket_len, lengths, encode, pooled_bf);
    wih_cvt_kernel<<<(G3 * D_ + 255) / 256, 256, 0, stream>>>(w_ih, wih_bf);
    gx_gemm_mfma<<<300, 256, 0, stream>>>(
        pooled_bf, wih_bf, b_ih, b_hh, gx2);
    gru_mfma_kernel<<<B_ / GROWS, 512, 0, stream>>>(
        lengths, w_hh, b_hh, h0, gx2, out);
}

// Round 22
// 81.597 us; speedup vs baseline: 1.9234x; 1.9234x over previous
//
#include <hip/hip_runtime.h>
#include <math.h>

#define B_ 256
#define S_ 50
#define K_ 20
#define D_ 128
#define G3 384          // 3*D
#define M_  (B_ * S_)   // 12800 (b,s) rows
#define GROWS 16        // batch rows per GRU block
#define KT 4            // k-tiles (32 wide): 128

typedef __attribute__((ext_vector_type(8))) short bf16x8;
typedef __attribute__((ext_vector_type(4))) float f32x4;

__device__ inline unsigned short bf16_rne(float f) {
    unsigned u = __float_as_uint(f);
    return (unsigned short)((u + 0x7fffu + ((u >> 16) & 1u)) >> 16);
}
__device__ inline float fsig(float x) {
    return __builtin_amdgcn_rcpf(1.f + __expf(-x));
}
__device__ inline float ftanh(float x) {
    float t = __expf(-2.f * fabsf(x));
    float r = (1.f - t) * __builtin_amdgcn_rcpf(1.f + t);
    return x >= 0.f ? r : -r;
}

#define WG_SYNC_LDS() do { \
    __builtin_amdgcn_sched_barrier(0); \
    asm volatile("s_waitcnt lgkmcnt(0)" ::: "memory"); \
    __builtin_amdgcn_s_barrier(); \
    __builtin_amdgcn_sched_barrier(0); \
} while (0)

// ---------------------------------------------------------------------------
// Kernel P: basket pooling -> bf16. unroll-4 pipelines the dependent gathers.
// ---------------------------------------------------------------------------
__global__ __launch_bounds__(256) void pool_kernel(
    const int* __restrict__ items, const int* __restrict__ basket_len,
    const int* __restrict__ lengths, const float* __restrict__ encode,
    unsigned short* __restrict__ pooled_bf)
{
    const int tid  = threadIdx.x;
    const int pair = tid >> 7;
    const int d    = tid & 127;
    const int m    = blockIdx.x * 2 + pair;
    const int b    = m / S_;
    const int s    = m % S_;
    const int len  = lengths[b];

    float p = 0.f;
    if (s < len) {
        const int  blen = basket_len[m];
        const int* it   = items + m * K_;
        #pragma unroll 4
        for (int k = 0; k < blen; ++k)
            p += encode[(long)it[k] * D_ + d];
        p /= (float)blen;
    }
    pooled_bf[m * D_ + d] = bf16_rne(p);
}

// ---------------------------------------------------------------------------
// Kernel W: w_ih f32 -> bf16 (one-time, 49152 elems).
// ---------------------------------------------------------------------------
__global__ __launch_bounds__(256) void wih_cvt_kernel(
    const float* __restrict__ w_ih, unsigned short* __restrict__ wih_bf)
{
    int i = blockIdx.x * 256 + threadIdx.x;
    if (i < G3 * D_) wih_bf[i] = bf16_rne(w_ih[i]);
}

// ---------------------------------------------------------------------------
// Kernel G v2 (R20 proven): MFMA GEMM, standard gx[row][n] output (coalesced
// across frow lanes). R21's [g][dim][s][b] relayout doubled FETCH (51200B
// lane stride -> one 64B line per 16B read) — reverted.
// ---------------------------------------------------------------------------
__global__ __launch_bounds__(256) void gx_gemm_mfma(
    const unsigned short* __restrict__ pooled_bf,
    const unsigned short* __restrict__ wih_bf,
    const float* __restrict__ b_ih, const float* __restrict__ b_hh,
    float* __restrict__ gx)
{
    __shared__ unsigned short Al[128 * 128];   // [m][k] swizzled, 32KB
    __shared__ unsigned short Bl[128 * 128];   // [n][k] swizzled, 32KB

    const int tid  = threadIdx.x;
    const int bm   = blockIdx.x % 100;
    const int bn   = blockIdx.x / 100;         // 0..2
    const int m0   = bm * 128;
    const int n0   = bn * 128;
    const int lane = tid & 63;
    const int wv   = tid >> 6;                 // 0..3
    const int frow = lane & 15;
    const int fhi  = lane >> 4;
    const int mh   = (wv & 1) * 64;
    const int nh   = (wv >> 1) * 64;

    #pragma unroll
    for (int i = 0; i < 8; ++i) {
        int idx = tid + i * 256;               // 0..2047
        int row = idx >> 4, c16 = idx & 15;
        int dst = (row * 256 + c16 * 16) ^ ((row & 7) << 4);
        *(bf16x8*)((char*)Al + dst) =
            *(const bf16x8*)(pooled_bf + (long)(m0 + row) * D_ + c16 * 8);
        *(bf16x8*)((char*)Bl + dst) =
            *(const bf16x8*)(wih_bf + (long)(n0 + row) * D_ + c16 * 8);
    }
    __syncthreads();

    bf16x8 af[4][KT], bfr[4][KT];
    #pragma unroll
    for (int t = 0; t < 4; ++t) {
        #pragma unroll
        for (int kt = 0; kt < KT; ++kt) {
            int ra = mh + t * 16 + frow;
            int oa = (ra * 256 + kt * 64 + fhi * 16) ^ ((ra & 7) << 4);
            af[t][kt] = *(const bf16x8*)((const char*)Al + oa);
            int rb = nh + t * 16 + frow;
            int ob = (rb * 256 + kt * 64 + fhi * 16) ^ ((rb & 7) << 4);
            bfr[t][kt] = *(const bf16x8*)((const char*)Bl + ob);
        }
    }

    f32x4 acc[4][4];
    #pragma unroll
    for (int mt = 0; mt < 4; ++mt)
        #pragma unroll
        for (int nt = 0; nt < 4; ++nt) {
            f32x4 c = {0.f, 0.f, 0.f, 0.f};
            #pragma unroll
            for (int kt = 0; kt < KT; ++kt)
                c = __builtin_amdgcn_mfma_f32_16x16x32_bf16(af[mt][kt], bfr[nt][kt], c, 0, 0, 0);
            acc[mt][nt] = c;
        }

    float bias[4];
    #pragma unroll
    for (int nt = 0; nt < 4; ++nt) {
        int n = n0 + nh + nt * 16 + frow;
        bias[nt] = b_ih[n] + (n < 2 * D_ ? b_hh[n] : 0.f);
    }

    #pragma unroll
    for (int mt = 0; mt < 4; ++mt) {
        #pragma unroll
        for (int nt = 0; nt < 4; ++nt) {
            int n = n0 + nh + nt * 16 + frow;
            #pragma unroll
            for (int r = 0; r < 4; ++r) {
                int row = m0 + mh + mt * 16 + fhi * 4 + r;
                gx[(long)row * G3 + n] = acc[mt][nt][r] + bias[nt];
            }
        }
    }
}

// ---------------------------------------------------------------------------
// Kernel B v10 (R19 proven, 56.2us): gates-in-registers, LDS-only barrier,
// distance-1 named double buffer. v11 (depth-2) and v12 (relayout) both
// regressed — this is the plateau config for the per-step chain.
// ---------------------------------------------------------------------------
__global__ __launch_bounds__(512, 1) void gru_mfma_kernel(
    const int* __restrict__ lengths, const float* __restrict__ w_hh,
    const float* __restrict__ b_hh, const float* __restrict__ h0,
    const float* __restrict__ gx, float* __restrict__ out)
{
    const int b0   = blockIdx.x * GROWS;
    const int tid  = threadIdx.x;
    const int lane = tid & 63;
    const int wv   = tid >> 6;
    const int frow = lane & 15;
    const int fhi  = lane >> 4;
    const int dim  = wv * 16 + frow;

    __shared__ unsigned short hb[2][GROWS * D_];

    bf16x8 wf[3][KT];
    #pragma unroll
    for (int g = 0; g < 3; ++g) {
        #pragma unroll
        for (int kt = 0; kt < KT; ++kt) {
            const float* wp = w_hh + (g * D_ + dim) * D_ + kt * 32 + fhi * 8;
            bf16x8 v;
            #pragma unroll
            for (int j = 0; j < 8; ++j) v[j] = (short)bf16_rne(wp[j]);
            wf[g][kt] = v;
        }
    }

    const float bhn_s = b_hh[2 * D_ + dim];

    int   mylen[4];
    float hp[4];
    #pragma unroll
    for (int r = 0; r < 4; ++r) {
        int row = fhi * 4 + r;
        mylen[r] = lengths[b0 + row];
        hp[r]    = h0[(long)(b0 + row) * D_ + dim];
        int wb = (row * 256 + dim * 2) ^ ((row & 7) << 4);
        *(unsigned short*)((char*)hb[0] + wb) = bf16_rne(hp[r]);
    }
    const int lenmax = lengths[b0];
    __syncthreads();

    float* ys = out;
    float* hu = out + (long)B_ * S_ * D_;

    const long gxrow[4] = {
        (long)(b0 + fhi * 4 + 0) * S_, (long)(b0 + fhi * 4 + 1) * S_,
        (long)(b0 + fhi * 4 + 2) * S_, (long)(b0 + fhi * 4 + 3) * S_ };

    #define GSTEP(s, CUR, NXT, PP) { \
        const int sn = ((s) + 1 < lenmax) ? (s) + 1 : lenmax - 1; \
        _Pragma("unroll") \
        for (int g = 0; g < 3; ++g) \
            _Pragma("unroll") \
            for (int r = 0; r < 4; ++r) \
                NXT[g][r] = gx[(gxrow[r] + sn) * G3 + g * 128 + dim]; \
        bf16x8 ah[KT]; \
        _Pragma("unroll") \
        for (int kt = 0; kt < KT; ++kt) { \
            int ab = (frow * 256 + kt * 64 + fhi * 16) ^ ((frow & 7) << 4); \
            ah[kt] = *(const bf16x8*)((const char*)hb[PP] + ab); \
        } \
        f32x4 cr = {0.f,0.f,0.f,0.f}, cz = {0.f,0.f,0.f,0.f}, cn = {0.f,0.f,0.f,0.f}; \
        _Pragma("unroll") \
        for (int kt = 0; kt < KT; ++kt) { \
            cr = __builtin_amdgcn_mfma_f32_16x16x32_bf16(ah[kt], wf[0][kt], cr, 0, 0, 0); \
            cz = __builtin_amdgcn_mfma_f32_16x16x32_bf16(ah[kt], wf[1][kt], cz, 0, 0, 0); \
            cn = __builtin_amdgcn_mfma_f32_16x16x32_bf16(ah[kt], wf[2][kt], cn, 0, 0, 0); \
        } \
        _Pragma("unroll") \
        for (int r = 0; r < 4; ++r) { \
            const int row = fhi * 4 + r; \
            const bool act = (s) < mylen[r]; \
            float rg = fsig(CUR[0][r] + cr[r]); \
            float zg = fsig(CUR[1][r] + cz[r]); \
            float ng = ftanh(CUR[2][r] + rg * (cn[r] + bhn_s)); \
            float hn = (1.f - zg) * ng + zg * hp[r]; \
            if (act) { \
                ys[(gxrow[r] + (s)) * D_ + dim] = hn; \
                hp[r] = hn; \
            } \
            int wb = (row * 256 + dim * 2) ^ ((row & 7) << 4); \
            *(unsigned short*)((char*)hb[(PP) ^ 1] + wb) = bf16_rne(hp[r]); \
        } \
        WG_SYNC_LDS(); \
    }

    float curA[3][4], curB[3][4];
    #pragma unroll
    for (int g = 0; g < 3; ++g)
        #pragma unroll
        for (int r = 0; r < 4; ++r)
            curA[g][r] = gx[(gxrow[r] + 0) * G3 + g * 128 + dim];

    int s = 0, pp = 0;
    while (s < lenmax) {
        GSTEP(s, curA, curB, pp);
        ++s; pp ^= 1;
        if (s >= lenmax) break;
        GSTEP(s, curB, curA, pp);
        ++s; pp ^= 1;
    }
    #undef GSTEP

    #pragma unroll
    for (int r = 0; r < 4; ++r) {
        const int row = fhi * 4 + r;
        hu[(long)(b0 + row) * D_ + dim] = hp[r];
        for (int t = mylen[r]; t < S_; ++t)
            ys[((long)(b0 + row) * S_ + t) * D_ + dim] = 0.f;
    }
}

extern "C" void kernel_launch(void* const* d_in, const int* in_sizes, int n_in,
                              void* d_out, int out_size, void* d_ws, size_t ws_size,
                              hipStream_t stream) {
    const int*   items      = (const int*)d_in[0];
    const int*   basket_len = (const int*)d_in[1];
    const int*   lengths    = (const int*)d_in[2];
    const float* encode     = (const float*)d_in[3];
    const float* w_ih       = (const float*)d_in[4];
    const float* w_hh       = (const float*)d_in[5];
    const float* b_ih       = (const float*)d_in[6];
    const float* b_hh       = (const float*)d_in[7];
    const float* h0         = (const float*)d_in[8];
    float* out = (float*)d_out;

    float*          gx        = (float*)d_ws;                    // 19.66 MB
    unsigned short* pooled_bf = (unsigned short*)(gx + (long)M_ * G3);  // 3.28 MB
    unsigned short* wih_bf    = pooled_bf + (long)M_ * D_;       // 96 KB

    pool_kernel<<<M_ / 2, 256, 0, stream>>>(
        items, basket_len, lengths, encode, pooled_bf);
    wih_cvt_kernel<<<(G3 * D_ + 255) / 256, 256, 0, stream>>>(w_ih, wih_bf);
    gx_gemm_mfma<<<300, 256, 0, stream>>>(
        pooled_bf, wih_bf, b_ih, b_hh, gx);
    gru_mfma_kernel<<<B_ / GROWS, 512, 0, stream>>>(
        lengths, w_hh, b_hh, h0, gx, out);
}